// Round 5
// baseline (260.808 us; speedup 1.0000x reference)
//
#include <hip/hip_runtime.h>

#define B 16384
#define D 1024
#define CL_ALPHA 0.5f
#define MAXM 16   // max samples per class; P(Poisson(1) > 16) ~ 1e-14 per class
#define INV_BD (1.0f / ((float)B * (float)D))

// ---------------------------------------------------------------------------
// Node 1 of 2: prep_kernel, 64 blocks x 256 threads.
// Each block builds the FULL 16384-bin histogram in LDS (zeroes its own LDS ->
// no global memset node; 64KB static LDS proven in R2). While scanning all of
// y_true (64KB, L2-hot after block 0), it stores member indices to global
// `list` only for its owned 256-class slice. Because the complete histogram is
// in-block, counts[kk] is an LDS read -> the whole metadata chain (m, kk, inv)
// resolves locally and is written as an order-preserving 16B desc[j]
// (R3 lesson: never reorder; blockIdx==j locality in the hot kernel).
// Replaces {memset, build, desc} = 3 nodes with 1. Block 0 zeroes out[0].
// ---------------------------------------------------------------------------
__global__ __launch_bounds__(256) void prep_kernel(const int* __restrict__ y_true,
                                                   int* __restrict__ list,
                                                   int4* __restrict__ desc,
                                                   float* __restrict__ out)
{
    __shared__ int hist[B];                       // 64KB
    const int t  = threadIdx.x;
    const int lo = blockIdx.x * 256;              // owned class slice [lo, lo+256)

#pragma unroll
    for (int w = 0; w < B / 256; ++w) hist[t + 256 * w] = 0;
    if (blockIdx.x == 0 && t == 0) out[0] = 0.0f;
    __syncthreads();

    // scan all 16384 labels: 16 int4 loads per thread, coalesced
    const int4* y4 = (const int4*)y_true;
#pragma unroll 4
    for (int w = 0; w < 16; ++w) {
        const int4 v = y4[t + 256 * w];
        const int i0 = 4 * (t + 256 * w);
        int s;
        s = atomicAdd(&hist[v.x], 1);
        if (v.x >= lo && v.x < lo + 256 && s < MAXM) list[v.x * MAXM + s] = i0;
        s = atomicAdd(&hist[v.y], 1);
        if (v.y >= lo && v.y < lo + 256 && s < MAXM) list[v.y * MAXM + s] = i0 + 1;
        s = atomicAdd(&hist[v.z], 1);
        if (v.z >= lo && v.z < lo + 256 && s < MAXM) list[v.z * MAXM + s] = i0 + 2;
        s = atomicAdd(&hist[v.w], 1);
        if (v.w >= lo && v.w < lo + 256 && s < MAXM) list[v.w * MAXM + s] = i0 + 3;
    }
    __syncthreads();

    // owned class j = lo + t: full metadata from LDS + one L2-hot load
    const int j  = lo + t;
    const int m  = hist[j];
    const int kk = y_true[j];                              // coalesced, L2-hot
    const float inv = CL_ALPHA / ((float)hist[kk] + 1.0f); // counts[kk] from LDS!
    desc[j] = make_int4(m, kk, __float_as_int(inv), 0);
}

// ---------------------------------------------------------------------------
// Node 2 of 2: class_kernel, one block per class, blockIdx.x == j (sequential
// row sweep), 256 threads, thread t owns float4 chunk t of each 4KB row.
// Trip 1: desc[j] (16B) + list4[j] (16B), independent, issued together.
// Trip 2: ALL rows (3 corr rows + up to 4 member rows), issued together.
// __launch_bounds__(256, 2): LOW min-waves floor so the register allocator may
// hold the 7-float4 payload in flight (R4 lesson: (256,6) -> VGPR=20 ->
// serialized loads -> 138us). Diagnostic: VGPR must come back >= ~60.
// Per-block atomicAdd(out) — no finalize node.
// ---------------------------------------------------------------------------
__global__ __launch_bounds__(256, 2) void class_kernel(const float* __restrict__ y_pred,
                                                       const float* __restrict__ centers,
                                                       const int* __restrict__ list,
                                                       const int4* __restrict__ desc,
                                                       float* __restrict__ out)
{
    const int t = threadIdx.x;
    const int j = blockIdx.x;

    const int4 d    = desc[j];                       // trip 1a
    const int4 mem4 = ((const int4*)list)[j * (MAXM / 4)];  // trip 1b (parallel)

    const int m = d.x;
    if (m == 0) return;                              // uniform; ~37.9% of blocks

    const int   kk  = d.y;
    const float inv = __int_as_float(d.z);
    const int   mm  = (m < MAXM) ? m : MAXM;

    // ---- trip 2: up to 7 independent row loads, all issued before corr ----
    const float4 cj = ((const float4*)(centers + (size_t)j  * D))[t];
    const float4 yj = ((const float4*)(y_pred  + (size_t)j  * D))[t];
    const float4 ck = ((const float4*)(centers + (size_t)kk * D))[t];

    float4 a0, a1, a2, a3;
    a0 = ((const float4*)(y_pred + (size_t)mem4.x * D))[t];            // m >= 1
    if (mm > 1) a1 = ((const float4*)(y_pred + (size_t)mem4.y * D))[t]; // wave-uniform
    if (mm > 2) a2 = ((const float4*)(y_pred + (size_t)mem4.z * D))[t];
    if (mm > 3) a3 = ((const float4*)(y_pred + (size_t)mem4.w * D))[t];

    // corr = inv*(ck - yj) - cj : first vmem wait lands here; member loads
    // (issued above) stay outstanding under counted vmcnt.
    float4 corr;
    corr.x = inv * (ck.x - yj.x) - cj.x;
    corr.y = inv * (ck.y - yj.y) - cj.y;
    corr.z = inv * (ck.z - yj.z) - cj.z;
    corr.w = inv * (ck.w - yj.w) - cj.w;

    float dx, dy, dz, dw;
    dx = a0.x + corr.x; dy = a0.y + corr.y; dz = a0.z + corr.z; dw = a0.w + corr.w;
    float acc = dx * dx + dy * dy + dz * dz + dw * dw;
    if (mm > 1) {
        dx = a1.x + corr.x; dy = a1.y + corr.y; dz = a1.z + corr.z; dw = a1.w + corr.w;
        acc += dx * dx + dy * dy + dz * dz + dw * dw;
    }
    if (mm > 2) {
        dx = a2.x + corr.x; dy = a2.y + corr.y; dz = a2.z + corr.z; dw = a2.w + corr.w;
        acc += dx * dx + dy * dy + dz * dz + dw * dw;
    }
    if (mm > 3) {
        dx = a3.x + corr.x; dy = a3.y + corr.y; dz = a3.z + corr.z; dw = a3.w + corr.w;
        acc += dx * dx + dy * dy + dz * dz + dw * dw;
    }
    for (int s = 4; s < mm; ++s) {                   // P(m>4 | m>0) ~ 0.6%
        const float4 a = ((const float4*)(y_pred + (size_t)list[j * MAXM + s] * D))[t];
        dx = a.x + corr.x; dy = a.y + corr.y; dz = a.z + corr.z; dw = a.w + corr.w;
        acc += dx * dx + dy * dy + dz * dz + dw * dw;
    }

    // ---- block reduce -> one atomicAdd ----
#pragma unroll
    for (int off = 32; off > 0; off >>= 1)
        acc += __shfl_down(acc, off, 64);

    __shared__ float smem[4];
    const int lane = t & 63;
    const int wid  = t >> 6;
    if (lane == 0) smem[wid] = acc;
    __syncthreads();
    if (t == 0) {
        const float tot = smem[0] + smem[1] + smem[2] + smem[3];
        atomicAdd(out, tot * INV_BD);
    }
}

extern "C" void kernel_launch(void* const* d_in, const int* in_sizes, int n_in,
                              void* d_out, int out_size, void* d_ws, size_t ws_size,
                              hipStream_t stream)
{
    const int*   y_true  = (const int*)d_in[0];
    const float* y_pred  = (const float*)d_in[1];
    const float* centers = (const float*)d_in[2];
    float* out = (float*)d_out;

    // Workspace: list 1MB | desc 256KB  (~1.25MB). No counts, no memset.
    int*  list = (int*)d_ws;
    int4* desc = (int4*)(list + B * MAXM);

    prep_kernel <<<64, 256, 0, stream>>>(y_true, list, desc, out);
    class_kernel<<<B,  256, 0, stream>>>(y_pred, centers, list, desc, out);
}

// Round 6
// 260.445 us; speedup vs baseline: 1.0014x; 1.0014x over previous
//
#include <hip/hip_runtime.h>

#define B 16384
#define D 1024
#define CL_ALPHA 0.5f
#define MAXM 16   // max samples per class; P(Poisson(1) > 16) ~ 1e-14 per class
#define INV_BD (1.0f / ((float)B * (float)D))

typedef float f4 __attribute__((ext_vector_type(4)));
typedef int   i4 __attribute__((ext_vector_type(4)));

// Inline-asm loads: force distinct destination registers so the payload stays
// in flight (R4/R5 lesson: C++ source pattern compiles to VGPR=16-20 and the
// scheduler serializes the loads with a vmcnt drain between each).
#define LOADX4F(dst, ptr) \
    asm volatile("global_load_dwordx4 %0, %1, off" : "=v"(dst) : "v"(ptr) : "memory")
#define LOADX4I(dst, ptr) \
    asm volatile("global_load_dwordx4 %0, %1, off" : "=v"(dst) : "v"(ptr) : "memory")
#define LOADD(dst, ptr) \
    asm volatile("global_load_dword %0, %1, off"   : "=v"(dst) : "v"(ptr) : "memory")
// Wait for ALL outstanding vmem, then fence the scheduler (guide rule #18:
// hipcc will hoist register-only consumers above an inline-asm waitcnt unless
// a sched_barrier(0) follows it).
#define WAITVM0 do { \
    asm volatile("s_waitcnt vmcnt(0)" ::: "memory"); \
    __builtin_amdgcn_sched_barrier(0); \
} while (0)

// ---------------------------------------------------------------------------
// Node 1 of 2: build_kernel, 64 blocks x 256 threads.
// Block b OWNS classes [b*256,(b+1)*256): scans all of y_true (64KB, L2-hot
// after block 0), histograms only its own slice in 1KB LDS, writes member
// list entries for its own classes, then writes its counts slice ONCE
// (owner-writes => no pre-zero => no memset node). Block 0 zeroes out[0].
// Unlike R5's prep (full 64KB histogram per block, ~35us), per-block LDS
// atomic work here is 1/64th: ~256 atomics per block.
// ---------------------------------------------------------------------------
__global__ __launch_bounds__(256) void build_kernel(const int* __restrict__ y_true,
                                                    int* __restrict__ counts,
                                                    int* __restrict__ list,
                                                    float* __restrict__ out)
{
    __shared__ int lh[256];
    const int t  = threadIdx.x;
    const int lo = blockIdx.x * 256;
    lh[t] = 0;
    if (blockIdx.x == 0 && t == 0) out[0] = 0.0f;
    __syncthreads();

    const int4* y4 = (const int4*)y_true;
#pragma unroll 4
    for (int w = 0; w < 16; ++w) {
        const int4 v  = y4[t + 256 * w];
        const int  i0 = 4 * (t + 256 * w);
        int s;
        if ((unsigned)(v.x - lo) < 256u) {
            s = atomicAdd(&lh[v.x - lo], 1); if (s < MAXM) list[v.x * MAXM + s] = i0;
        }
        if ((unsigned)(v.y - lo) < 256u) {
            s = atomicAdd(&lh[v.y - lo], 1); if (s < MAXM) list[v.y * MAXM + s] = i0 + 1;
        }
        if ((unsigned)(v.z - lo) < 256u) {
            s = atomicAdd(&lh[v.z - lo], 1); if (s < MAXM) list[v.z * MAXM + s] = i0 + 2;
        }
        if ((unsigned)(v.w - lo) < 256u) {
            s = atomicAdd(&lh[v.w - lo], 1); if (s < MAXM) list[v.w * MAXM + s] = i0 + 3;
        }
    }
    __syncthreads();
    counts[lo + t] = lh[t];     // owner write: exactly once per class
}

// ---------------------------------------------------------------------------
// Node 2 of 2: class_kernel, one block per class (blockIdx.x == j, sequential
// row locality — R3 lesson), 256 threads, thread t owns float4 chunk t.
// TWO explicit memory levels, asm-pipelined:
//   L0: counts[j] | y_true[j] | list4[j]      (3 loads, 1 wait)
//   L1: cj | yj | ck | counts[kk] | a0..a3    (8 loads, 1 wait)
// inv = alpha/(counts[kk]+1) is only consumed at the final FMA, so counts[kk]
// rides level 1 — the desc precompute pass is unnecessary.
// Corr rows issued only for nonempty blocks (keeps FETCH ~94MB: empty classes
// fetch 12B, not 8KB). Missing member rows alias member 0 (L1-coalesced) with
// weight 0. Per-block atomicAdd(out) — no finalize node.
// NO __launch_bounds__ second arg (R4/R5: occupancy hints poisoned regalloc).
// ---------------------------------------------------------------------------
__global__ __launch_bounds__(256) void class_kernel(const int* __restrict__ y_true,
                                                    const float* __restrict__ y_pred,
                                                    const float* __restrict__ centers,
                                                    const int* __restrict__ counts,
                                                    const int* __restrict__ list,
                                                    float* __restrict__ out)
{
    const int t = threadIdx.x;
    const int j = blockIdx.x;

    // ---- level 0: three independent metadata loads, one wait ----
    int m_, kk_;
    i4 mem4;
    LOADD  (m_,   counts + j);
    LOADD  (kk_,  y_true + j);
    LOADX4I(mem4, (const i4*)(list + j * MAXM));
    WAITVM0;

    const int m = m_;
    if (m == 0) return;                  // uniform per block; nothing outstanding

    const int kk = kk_;
    const int mm = (m < MAXM) ? m : MAXM;
    const int i0 = mem4[0];
    const int i1 = (mm > 1) ? mem4[1] : i0;   // alias -> same line, L1/MSHR hit
    const int i2 = (mm > 2) ? mem4[2] : i0;
    const int i3 = (mm > 3) ? mem4[3] : i0;

    // ---- level 1: eight independent loads, all in flight, one wait ----
    f4 cj, yj, ck, a0, a1, a2, a3;
    int ckk_;
    LOADX4F(cj, (const f4*)(centers + (size_t)j  * D) + t);
    LOADX4F(yj, (const f4*)(y_pred  + (size_t)j  * D) + t);
    LOADX4F(ck, (const f4*)(centers + (size_t)kk * D) + t);
    LOADD  (ckk_, counts + kk);
    LOADX4F(a0, (const f4*)(y_pred + (size_t)i0 * D) + t);
    LOADX4F(a1, (const f4*)(y_pred + (size_t)i1 * D) + t);
    LOADX4F(a2, (const f4*)(y_pred + (size_t)i2 * D) + t);
    LOADX4F(a3, (const f4*)(y_pred + (size_t)i3 * D) + t);
    WAITVM0;

    const float inv = CL_ALPHA / ((float)ckk_ + 1.0f);   // same formula as verified

    f4 corr;
    corr[0] = inv * (ck[0] - yj[0]) - cj[0];
    corr[1] = inv * (ck[1] - yj[1]) - cj[1];
    corr[2] = inv * (ck[2] - yj[2]) - cj[2];
    corr[3] = inv * (ck[3] - yj[3]) - cj[3];

    const float w1 = (mm > 1) ? 1.0f : 0.0f;
    const float w2 = (mm > 2) ? 1.0f : 0.0f;
    const float w3 = (mm > 3) ? 1.0f : 0.0f;

    float dx, dy, dz, dw, s;
    dx = a0[0] + corr[0]; dy = a0[1] + corr[1]; dz = a0[2] + corr[2]; dw = a0[3] + corr[3];
    float acc = dx * dx + dy * dy + dz * dz + dw * dw;

    dx = a1[0] + corr[0]; dy = a1[1] + corr[1]; dz = a1[2] + corr[2]; dw = a1[3] + corr[3];
    s = dx * dx + dy * dy + dz * dz + dw * dw;
    acc += w1 * s;

    dx = a2[0] + corr[0]; dy = a2[1] + corr[1]; dz = a2[2] + corr[2]; dw = a2[3] + corr[3];
    s = dx * dx + dy * dy + dz * dz + dw * dw;
    acc += w2 * s;

    dx = a3[0] + corr[0]; dy = a3[1] + corr[1]; dz = a3[2] + corr[2]; dw = a3[3] + corr[3];
    s = dx * dx + dy * dy + dz * dz + dw * dw;
    acc += w3 * s;

    for (int q = 4; q < mm; ++q) {       // P(m>4 | m>0) ~ 0.6%: rare, plain loads
        const float4 a = ((const float4*)(y_pred + (size_t)list[j * MAXM + q] * D))[t];
        dx = a.x + corr[0]; dy = a.y + corr[1]; dz = a.z + corr[2]; dw = a.w + corr[3];
        acc += dx * dx + dy * dy + dz * dz + dw * dw;
    }

    // ---- block reduce -> one atomicAdd ----
#pragma unroll
    for (int off = 32; off > 0; off >>= 1)
        acc += __shfl_down(acc, off, 64);

    __shared__ float smem[4];
    const int lane = t & 63;
    const int wid  = t >> 6;
    if (lane == 0) smem[wid] = acc;
    __syncthreads();
    if (t == 0) {
        const float tot = smem[0] + smem[1] + smem[2] + smem[3];
        atomicAdd(out, tot * INV_BD);
    }
}

extern "C" void kernel_launch(void* const* d_in, const int* in_sizes, int n_in,
                              void* d_out, int out_size, void* d_ws, size_t ws_size,
                              hipStream_t stream)
{
    const int*   y_true  = (const int*)d_in[0];
    const float* y_pred  = (const float*)d_in[1];
    const float* centers = (const float*)d_in[2];
    float* out = (float*)d_out;

    // Workspace: counts 64KB | list 1MB. No memset, no desc.
    int* counts = (int*)d_ws;
    int* list   = counts + B;

    build_kernel<<<64, 256, 0, stream>>>(y_true, counts, list, out);
    class_kernel<<<B,  256, 0, stream>>>(y_true, y_pred, centers, counts, list, out);
}